// Round 7
// baseline (212.983 us; speedup 1.0000x reference)
//
#include <hip/hip_runtime.h>
#include <stdint.h>
#include <stddef.h>

typedef unsigned short u16;
typedef unsigned int   u32;
typedef unsigned short u16x8 __attribute__((ext_vector_type(8)));
typedef __attribute__((ext_vector_type(8))) __bf16 bf16x8;
typedef __attribute__((ext_vector_type(4))) float f32x4;

__device__ __forceinline__ float bf2f(u16 v){
  union { unsigned u; float f; } x; x.u = ((unsigned)v) << 16; return x.f;
}
__device__ __forceinline__ u16 f2bf(float f){
  union { float f; unsigned u; } x; x.f = f;
  return (u16)((x.u + 0x7fffu + ((x.u >> 16) & 1u)) >> 16);
}

__device__ __forceinline__ float exp2_fast(float x){
  float r; asm("v_exp_f32 %0, %1" : "=v"(r) : "v"(x)); return r;
}
__device__ __forceinline__ u32 cvt_pk_bf16(float lo, float hi){
  u32 r; asm("v_cvt_pk_bf16_f32 %0, %1, %2" : "=v"(r) : "v"(lo), "v"(hi)); return r;
}

__device__ __forceinline__ f32x4 mfma16(bf16x8 a, bf16x8 b, f32x4 c){
  return __builtin_amdgcn_mfma_f32_16x16x32_bf16(a, b, c, 0, 0, 0);
}

#define AS1 __attribute__((address_space(1)))
#define AS3 __attribute__((address_space(3)))
__device__ __forceinline__ void gload_lds16(const void* g, void* l){
  __builtin_amdgcn_global_load_lds((const AS1 void*)g, (AS3 void*)l, 16, 0, 0);
}

// ---------------- fp32 -> bf16, PRE-SWIZZLED chunks for BK=64 GEMM tiles ----
// 16B chunk at (row, c) stored at position (c&~7)|((c&7)^(row&7)).
// rows*K elements, K=1024 -> 128 chunks/row.
__global__ void f32_to_bf16_swz(const float* __restrict__ in, u16* __restrict__ out,
                                int total_chunks){
  for (int i = blockIdx.x * blockDim.x + threadIdx.x; i < total_chunks;
       i += gridDim.x * blockDim.x){
    int row = i >> 7, c = i & 127;
    int cs = (c & ~7) | ((c & 7) ^ (row & 7));
    const float* p = in + ((size_t)i << 3);
    float4 v0 = *(const float4*)p;
    float4 v1 = *(const float4*)(p + 4);
    u16x8 o = { f2bf(v0.x), f2bf(v0.y), f2bf(v0.z), f2bf(v0.w),
                f2bf(v1.x), f2bf(v1.y), f2bf(v1.z), f2bf(v1.w) };
    *(u16x8*)(out + (((size_t)row << 7) + cs) * 8) = o;
  }
}

// ---------------- transpose+convert fp32 (R x C) -> bf16 (C x R), swizzled --
// Output row-length R (=K=1024 for all weights); same chunk swizzle as above.
__global__ void conv_transpose_swz(const float* __restrict__ in, u16* __restrict__ out,
                                   int R, int C){
  __shared__ float t[32][33];
  int c0 = blockIdx.x * 32, r0 = blockIdx.y * 32;
  int tx = threadIdx.x, ty = threadIdx.y;
  t[ty][tx] = in[(size_t)(r0 + ty) * C + c0 + tx];
  __syncthreads();
  int tid = ty * 32 + tx;
  if (tid < 128){
    int orow = tid >> 2, oc = tid & 3;     // out-row offset, chunk-in-tile
    int gr = c0 + orow;                    // out global row
    int gc = (r0 >> 3) + oc;               // out global chunk col
    int gcs = (gc & ~7) | ((gc & 7) ^ (gr & 7));
    u16x8 v;
#pragma unroll
    for (int i = 0; i < 8; i++) v[i] = f2bf(t[oc * 8 + i][orow]);
    *(u16x8*)(out + (size_t)gr * R + gcs * 8) = v;
  }
}

// ---------------- GEMM 256x128, BK=64, 8 waves, 3-buffer counted-vmcnt ------
// A (M x K) and Bt (N x K) are PRE-SWIZZLED (chunk ^ row&7 within 8-groups).
// Per-wave output 128x32 (wr in {0,1} x wcn in {0..3}); acc[8][2].
template<bool F32OUT>
__global__ __launch_bounds__(512, 2)
void gemm8(const u16* __restrict__ A, const u16* __restrict__ Bt,
           void* __restrict__ Cv, int M, int N, int K){
  __shared__ __align__(16) u16 Ab[3][256 * 64];
  __shared__ __align__(16) u16 Bb[3][128 * 64];
  const int tid = threadIdx.x;
  const int wid = tid >> 6, lane = tid & 63;
  const int g = lane >> 4, col = lane & 15;
  const int wr = wid >> 2, wcn = wid & 3;

  // XCD-aware swizzle (grid size multiple of 8)
  int nb  = gridDim.x * gridDim.y;
  int lid = blockIdx.y * gridDim.x + blockIdx.x;
  int cpx = nb >> 3;
  int sid = (lid & 7) * cpx + (lid >> 3);
  int bx  = sid % gridDim.x, by = sid / gridDim.x;
  const int m0 = by * 256, n0 = bx * 128;

  f32x4 acc[8][2];
#pragma unroll
  for (int i = 0; i < 8; i++)
#pragma unroll
    for (int j = 0; j < 2; j++) acc[i][j] = (f32x4){0.f, 0.f, 0.f, 0.f};

  const int srow = wid * 8 + (lane >> 3);   // + j*64
  const int scl  = (lane & 7) * 8;
  const int swz  = col & 7;

  auto STAGE = [&](int bi, int k0){
#pragma unroll
    for (int j = 0; j < 4; j++)
      gload_lds16(A + (size_t)(m0 + j * 64 + srow) * K + k0 + scl,
                  &Ab[bi][j * 4096 + wid * 512]);
#pragma unroll
    for (int j = 0; j < 2; j++)
      gload_lds16(Bt + (size_t)(n0 + j * 64 + srow) * K + k0 + scl,
                  &Bb[bi][j * 4096 + wid * 512]);
  };

  const int NT = K / 64;
  STAGE(0, 0);
  STAGE(1, 64);
  asm volatile("s_waitcnt vmcnt(6)");        // tile0's 6 loads done
  __builtin_amdgcn_sched_barrier(0);
  __builtin_amdgcn_s_barrier();
  __builtin_amdgcn_sched_barrier(0);

  int cb = 0, sb = 2;
  for (int t = 0; t < NT; ++t){
    if (t + 2 < NT) STAGE(sb, (t + 2) * 64);

    bf16x8 bfr[2][2];
#pragma unroll
    for (int ni = 0; ni < 2; ni++){
      int row = wcn * 32 + ni * 16 + col;
#pragma unroll
      for (int ks = 0; ks < 2; ks++)
        bfr[ni][ks] = *(const bf16x8*)&Bb[cb][row * 64 + (((ks * 4 + g) ^ swz) << 3)];
    }
#pragma unroll
    for (int q = 0; q < 4; q++){
      bf16x8 afr[2][2];
#pragma unroll
      for (int m2 = 0; m2 < 2; m2++){
        int row = wr * 128 + q * 32 + m2 * 16 + col;
#pragma unroll
        for (int ks = 0; ks < 2; ks++)
          afr[m2][ks] = *(const bf16x8*)&Ab[cb][row * 64 + (((ks * 4 + g) ^ swz) << 3)];
      }
      __builtin_amdgcn_s_setprio(1);
#pragma unroll
      for (int m2 = 0; m2 < 2; m2++)
#pragma unroll
        for (int ni = 0; ni < 2; ni++)
#pragma unroll
          for (int ks = 0; ks < 2; ks++)
            acc[q * 2 + m2][ni] = mfma16(afr[m2][ks], bfr[ni][ks], acc[q * 2 + m2][ni]);
      __builtin_amdgcn_s_setprio(0);
    }

    // boundary: tile t+1's loads (oldest) must land; t+2's 6 stay in flight
    if (t + 2 < NT) asm volatile("s_waitcnt vmcnt(6)");
    else            asm volatile("s_waitcnt vmcnt(0)");
    __builtin_amdgcn_sched_barrier(0);
    __builtin_amdgcn_s_barrier();
    __builtin_amdgcn_sched_barrier(0);
    cb = (cb == 2) ? 0 : cb + 1;
    sb = (sb == 2) ? 0 : sb + 1;
  }

#pragma unroll
  for (int mi = 0; mi < 8; mi++)
#pragma unroll
    for (int ni = 0; ni < 2; ni++)
#pragma unroll
      for (int r = 0; r < 4; r++){
        int row = m0 + wr * 128 + mi * 16 + g * 4 + r;
        int cc  = n0 + wcn * 32 + ni * 16 + col;
        if (F32OUT) ((float*)Cv)[(size_t)row * N + cc] = acc[mi][ni][r];
        else        ((u16*)Cv)[(size_t)row * N + cc] = f2bf(acc[mi][ni][r]);
      }
}

// ---------------- prep Q: RMSNorm+RoPE, QKV(b,s,2048) -> Qn (b,h,s,d) -------
__global__ void prep_q(const u16* __restrict__ qkv, u16* __restrict__ Qn,
                       const float* __restrict__ cosb, const float* __restrict__ sinb,
                       const float* __restrict__ w){
  int gid = blockIdx.x * 4 + (threadIdx.x >> 6);   // (b*16+h)*2048 + s
  int lane = threadIdx.x & 63;
  int s = gid & 2047;
  int bh = gid >> 11;
  int h = bh & 15, b = bh >> 4;
  float x = bf2f(qkv[((size_t)(b * 2048 + s)) * 2048 + h * 64 + lane]);
  float ss = x * x;
#pragma unroll
  for (int off = 32; off >= 1; off >>= 1) ss += __shfl_xor(ss, off, 64);
  float y = x * rsqrtf(ss * (1.f / 64.f) + 1e-6f);
  y *= w[lane];
  float yp = __shfl_xor(y, 16, 64);
  float rot = (lane & 16) ? yp : -yp;
  Qn[(size_t)gid * 64 + lane] = f2bf(y * cosb[s * 64 + lane] + rot * sinb[s * 64 + lane]);
}

// ---------------- prep K: RMSNorm+RoPE -> Kn (b,kvh,s,d) PRE-SWIZZLED -------
__global__ void prep_k(const u16* __restrict__ qkv, u16* __restrict__ Kn,
                       const float* __restrict__ cosb, const float* __restrict__ sinb,
                       const float* __restrict__ w){
  int gid = blockIdx.x * 4 + (threadIdx.x >> 6);   // (b*8+kvh)*2048 + s
  int lane = threadIdx.x & 63;
  int s = gid & 2047;
  int bk = gid >> 11;
  int kvh = bk & 7, b = bk >> 3;
  float x = bf2f(qkv[((size_t)(b * 2048 + s)) * 2048 + 1024 + kvh * 64 + lane]);
  float ss = x * x;
#pragma unroll
  for (int off = 32; off >= 1; off >>= 1) ss += __shfl_xor(ss, off, 64);
  float y = x * rsqrtf(ss * (1.f / 64.f) + 1e-6f);
  y *= w[lane];
  float yp = __shfl_xor(y, 16, 64);
  float rot = (lane & 16) ? yp : -yp;
  int swz = ((((lane >> 3) ^ s) & 7) << 3) | (lane & 7);
  Kn[(size_t)gid * 64 + swz] = f2bf(y * cosb[s * 64 + lane] + rot * sinb[s * 64 + lane]);
}

// ---------------- prep V: RMSNorm + transpose -> Vn (b,kvh,d,s) swizzled ----
__global__ __launch_bounds__(256)
void prep_v(const u16* __restrict__ qkv, u16* __restrict__ Vn){
  int blk = blockIdx.x;                 // b*256 + kvh*32 + stile
  int stile = blk & 31, kvh = (blk >> 5) & 7, b = blk >> 8;
  int wid = threadIdx.x >> 6, lane = threadIdx.x & 63;
  __shared__ u16 T[64][68];
#pragma unroll 4
  for (int j = 0; j < 16; j++){
    int sl = wid * 16 + j;
    int s = stile * 64 + sl;
    float x = bf2f(qkv[((size_t)(b * 2048 + s)) * 2048 + 1536 + kvh * 64 + lane]);
    float ss = x * x;
#pragma unroll
    for (int off = 32; off >= 1; off >>= 1) ss += __shfl_xor(ss, off, 64);
    T[sl][lane] = f2bf(x * rsqrtf(ss * (1.f / 64.f) + 1e-6f));
  }
  __syncthreads();
  size_t obase = ((size_t)(b * 8 + kvh) * 64) * 2048 + stile * 64;
#pragma unroll
  for (int it = 0; it < 2; it++){
    int t = it * 256 + threadIdx.x;
    int d = t >> 3, c = t & 7;
    int cl = c ^ (d & 7);
    u16x8 v;
#pragma unroll
    for (int i = 0; i < 8; i++) v[i] = T[cl * 8 + i][d];
    *(u16x8*)(Vn + obase + (size_t)d * 2048 + c * 8) = v;
  }
}

// ---------------- Flash attention (no-max softmax, 256q/block, 4 cg) --------
// Qn (b,h,s,d); Kn (b,kvh,s,d) swz; Vn (b,kvh,d,s) swz; AO (b,s,h,d) swz.
__global__ __launch_bounds__(256, 2)
void flash_attn(const u16* __restrict__ Qn, const u16* __restrict__ Kn,
                const u16* __restrict__ Vn, u16* __restrict__ AO){
  const int S = 2048;
  const float L2E = 1.4426950408889634f;
  const float C2 = 30.f;
  const int b = blockIdx.z, h = blockIdx.y, qt = blockIdx.x;
  const int kvh = h >> 1;
  const int wid = threadIdx.x >> 6, lane = threadIdx.x & 63;
  const int g = lane >> 4, col = lane & 15;
  const int q0 = qt * 256 + wid * 64;

  __shared__ __align__(16) u16 Klds[2][64 * 64];   // [s][d] chunks ^ (s&7)
  __shared__ __align__(16) u16 Vlds[2][64 * 64];   // [d][s] chunks ^ (d&7)
  __shared__ __align__(16) u16 Plds[4][16 * 64];   // per-wave 2KB, reused per cg

  bf16x8 ones;
#pragma unroll
  for (int i = 0; i < 8; i++) ones[i] = (__bf16)1.0f;

  bf16x8 aq[4][2];
#pragma unroll
  for (int cg = 0; cg < 4; cg++){
    const u16* qp = Qn + ((size_t)((b * 16 + h) * S) + q0 + cg * 16 + col) * 64;
    aq[cg][0] = *(const bf16x8*)(qp + g * 8);
    aq[cg][1] = *(const bf16x8*)(qp + 32 + g * 8);
  }

  const u16* Kbase = Kn + (size_t)(b * 8 + kvh) * S * 64;
  const u16* Vbase = Vn + (size_t)(b * 8 + kvh) * 64 * S;

  f32x4 acc[4][4];
  f32x4 lacc[4];
#pragma unroll
  for (int cg = 0; cg < 4; cg++){
    lacc[cg] = (f32x4){0.f, 0.f, 0.f, 0.f};
#pragma unroll
    for (int i = 0; i < 4; i++) acc[cg][i] = (f32x4){0.f, 0.f, 0.f, 0.f};
  }

  const int sw = col & 7;
  const int pswz = sw << 4;
  char* Pw = (char*)&Plds[wid][0];

  auto STAGE = [&](int bi, int kt){
    int kc0 = kt * 64;
#pragma unroll
    for (int cc = 0; cc < 2; cc++){
      int chunk = cc * 4 + wid;
      gload_lds16(Kbase + (size_t)kc0 * 64 + chunk * 512 + lane * 8,
                  &Klds[bi][chunk * 512]);
      int drow = chunk * 8 + (lane >> 3);
      gload_lds16(Vbase + (size_t)drow * S + kc0 + (lane & 7) * 8,
                  &Vlds[bi][chunk * 512]);
    }
  };

  int buf = 0;
  STAGE(0, 0);
  __syncthreads();

  for (int kt = 0; kt < S / 64; ++kt){
    if (kt + 1 < S / 64) STAGE(buf ^ 1, kt + 1);

    const u16* Kb = &Klds[buf][0];
    const u16* Vb = &Vlds[buf][0];

    bf16x8 kf[4][2], vf[4][2];
#pragma unroll
    for (int c = 0; c < 4; c++){
      const u16* kb = Kb + (c * 16 + col) * 64;
      kf[c][0] = *(const bf16x8*)(kb + (g ^ sw) * 8);
      kf[c][1] = *(const bf16x8*)(kb + ((4 + g) ^ sw) * 8);
      const u16* vb = Vb + (c * 16 + col) * 64;
      vf[c][0] = *(const bf16x8*)(vb + (g ^ sw) * 8);
      vf[c][1] = *(const bf16x8*)(vb + ((4 + g) ^ sw) * 8);
    }

#pragma unroll
    for (int cg = 0; cg < 4; cg++){
      f32x4 sf[4];
      __builtin_amdgcn_s_setprio(1);
#pragma unroll
      for (int c = 0; c < 4; c++){
        f32x4 z = (f32x4){0.f, 0.f, 0.f, 0.f};
        z = mfma16(kf[c][0], aq[cg][0], z);
        sf[c] = mfma16(kf[c][1], aq[cg][1], z);
      }
      __builtin_amdgcn_s_setprio(0);

#pragma unroll
      for (int c = 0; c < 4; c++){
        float p0 = exp2_fast(__builtin_fmaf(sf[c][0], L2E, -C2));
        float p1 = exp2_fast(__builtin_fmaf(sf[c][1], L2E, -C2));
        float p2 = exp2_fast(__builtin_fmaf(sf[c][2], L2E, -C2));
        float p3 = exp2_fast(__builtin_fmaf(sf[c][3], L2E, -C2));
        uint2 pw;
        pw.x = cvt_pk_bf16(p0, p1);
        pw.y = cvt_pk_bf16(p2, p3);
        *(uint2*)(Pw + ((col * 128 + c * 32 + g * 8) ^ pswz)) = pw;
      }

      bf16x8 pf0 = *(const bf16x8*)(Pw + ((col * 128 + g * 16) ^ pswz));
      bf16x8 pf1 = *(const bf16x8*)(Pw + ((col * 128 + 64 + g * 16) ^ pswz));
      __builtin_amdgcn_s_setprio(1);
#pragma unroll
      for (int cd = 0; cd < 4; cd++){
        acc[cg][cd] = mfma16(vf[cd][0], pf0, acc[cg][cd]);
        acc[cg][cd] = mfma16(vf[cd][1], pf1, acc[cg][cd]);
      }
      lacc[cg] = mfma16(ones, pf0, lacc[cg]);
      lacc[cg] = mfma16(ones, pf1, lacc[cg]);
      __builtin_amdgcn_s_setprio(0);
    }

    __syncthreads();
    buf ^= 1;
  }

#pragma unroll
  for (int cg = 0; cg < 4; cg++){
    float linv = 1.f / lacc[cg][0];
    int s = q0 + cg * 16 + col;
#pragma unroll
    for (int cd = 0; cd < 4; cd++){
      uint2 o;
      o.x = cvt_pk_bf16(acc[cg][cd][0] * linv, acc[cg][cd][1] * linv);
      o.y = cvt_pk_bf16(acc[cg][cd][2] * linv, acc[cg][cd][3] * linv);
      // pre-swizzled for the Wo GEMM: chunk (cd*2 + (g>>1)) ^ (s&7) in group h*8
      int pc = (cd * 2 + (g >> 1)) ^ sw;
      *(uint2*)(AO + (size_t)(b * S + s) * 1024 + h * 64 + pc * 8 + (g & 1) * 4) = o;
    }
  }
}

// ---------------- host-side launch ------------------------------------------
extern "C" void kernel_launch(void* const* d_in, const int* in_sizes, int n_in,
                              void* d_out, int out_size, void* d_ws, size_t ws_size,
                              hipStream_t stream){
  const int Btok = 8192;          // B*S
  const float* hs   = (const float*)d_in[0];
  const float* cosb = (const float*)d_in[1];
  const float* sinb = (const float*)d_in[2];
  const float* Wq = (const float*)d_in[5];
  const float* Wk = (const float*)d_in[6];
  const float* Wv = (const float*)d_in[7];
  const float* Wo = (const float*)d_in[8];
  const float* qw = (const float*)d_in[9];
  const float* kw = (const float*)d_in[10];
  float* out = (float*)d_out;

  char* ws = (char*)d_ws;
  u16* hsB   = (u16*)ws;               ws += (size_t)Btok * 1024 * 2;   // 16MB
  u16* WqkvT = (u16*)ws;               ws += (size_t)2048 * 1024 * 2;   // 4MB
  u16* WoT   = (u16*)ws;               ws += (size_t)1024 * 1024 * 2;   // 2MB
  u16* QKV   = (u16*)ws;               ws += (size_t)Btok * 2048 * 2;   // 32MB
  u16* Qn    = (u16*)ws;               ws += (size_t)Btok * 1024 * 2;   // 16MB
  u16* Kn    = (u16*)ws;               ws += (size_t)Btok * 512  * 2;   // 8MB
  u16* Vn    = (u16*)ws;               ws += (size_t)Btok * 512  * 2;   // 8MB
  u16* AO    = hsB;                    // alias: hsB dead after QKV GEMM

  f32_to_bf16_swz<<<2048, 256, 0, stream>>>(hs, hsB, Btok * 128);

  dim3 tb(32, 32);
  conv_transpose_swz<<<dim3(32, 32), tb, 0, stream>>>(Wq, WqkvT,               1024, 1024);
  conv_transpose_swz<<<dim3(16, 32), tb, 0, stream>>>(Wk, WqkvT + 1024 * 1024, 1024, 512);
  conv_transpose_swz<<<dim3(16, 32), tb, 0, stream>>>(Wv, WqkvT + 1536 * 1024, 1024, 512);
  conv_transpose_swz<<<dim3(32, 32), tb, 0, stream>>>(Wo, WoT,                 1024, 1024);

  gemm8<false><<<dim3(16, 32), 512, 0, stream>>>(hsB, WqkvT, QKV, Btok, 2048, 1024);

  prep_q<<<32768, 256, 0, stream>>>(QKV, Qn, cosb, sinb, qw);
  prep_k<<<16384, 256, 0, stream>>>(QKV, Kn, cosb, sinb, kw);
  prep_v<<<1024, 256, 0, stream>>>(QKV, Vn);

  flash_attn<<<dim3(8, 16, 4), 256, 0, stream>>>(Qn, Kn, Vn, AO);

  gemm8<true><<<dim3(8, 32), 512, 0, stream>>>(AO, WoT, out, Btok, 1024, 1024);
}

// Round 8
// 205.215 us; speedup vs baseline: 1.0379x; 1.0379x over previous
//
#include <hip/hip_runtime.h>
#include <stdint.h>
#include <stddef.h>

typedef unsigned short u16;
typedef unsigned int   u32;
typedef unsigned short u16x8 __attribute__((ext_vector_type(8)));
typedef __attribute__((ext_vector_type(8))) __bf16 bf16x8;
typedef __attribute__((ext_vector_type(4))) float f32x4;

__device__ __forceinline__ float bf2f(u16 v){
  union { unsigned u; float f; } x; x.u = ((unsigned)v) << 16; return x.f;
}
__device__ __forceinline__ u16 f2bf(float f){
  union { float f; unsigned u; } x; x.f = f;
  return (u16)((x.u + 0x7fffu + ((x.u >> 16) & 1u)) >> 16);
}

__device__ __forceinline__ float exp2_fast(float x){
  float r; asm("v_exp_f32 %0, %1" : "=v"(r) : "v"(x)); return r;
}
__device__ __forceinline__ u32 cvt_pk_bf16(float lo, float hi){
  u32 r; asm("v_cvt_pk_bf16_f32 %0, %1, %2" : "=v"(r) : "v"(lo), "v"(hi)); return r;
}

__device__ __forceinline__ f32x4 mfma16(bf16x8 a, bf16x8 b, f32x4 c){
  return __builtin_amdgcn_mfma_f32_16x16x32_bf16(a, b, c, 0, 0, 0);
}

#define AS1 __attribute__((address_space(1)))
#define AS3 __attribute__((address_space(3)))
__device__ __forceinline__ void gload_lds16(const void* g, void* l){
  __builtin_amdgcn_global_load_lds((const AS1 void*)g, (AS3 void*)l, 16, 0, 0);
}

// ---------------- fp32 -> bf16, PRE-SWIZZLED chunks for BK=64 GEMM tiles ----
// 16B chunk at (row, c) stored at position (c&~7)|((c&7)^(row&7)).
__global__ void f32_to_bf16_swz(const float* __restrict__ in, u16* __restrict__ out,
                                int total_chunks){
  for (int i = blockIdx.x * blockDim.x + threadIdx.x; i < total_chunks;
       i += gridDim.x * blockDim.x){
    int row = i >> 7, c = i & 127;
    int cs = (c & ~7) | ((c & 7) ^ (row & 7));
    const float* p = in + ((size_t)i << 3);
    float4 v0 = *(const float4*)p;
    float4 v1 = *(const float4*)(p + 4);
    u16x8 o = { f2bf(v0.x), f2bf(v0.y), f2bf(v0.z), f2bf(v0.w),
                f2bf(v1.x), f2bf(v1.y), f2bf(v1.z), f2bf(v1.w) };
    *(u16x8*)(out + (((size_t)row << 7) + cs) * 8) = o;
  }
}

// ---------------- transpose+convert fp32 (R x C) -> bf16 (C x R), swizzled --
__global__ void conv_transpose_swz(const float* __restrict__ in, u16* __restrict__ out,
                                   int R, int C){
  __shared__ float t[32][33];
  int c0 = blockIdx.x * 32, r0 = blockIdx.y * 32;
  int tx = threadIdx.x, ty = threadIdx.y;
  t[ty][tx] = in[(size_t)(r0 + ty) * C + c0 + tx];
  __syncthreads();
  int tid = ty * 32 + tx;
  if (tid < 128){
    int orow = tid >> 2, oc = tid & 3;
    int gr = c0 + orow;
    int gc = (r0 >> 3) + oc;
    int gcs = (gc & ~7) | ((gc & 7) ^ (gr & 7));
    u16x8 v;
#pragma unroll
    for (int i = 0; i < 8; i++) v[i] = f2bf(t[oc * 8 + i][orow]);
    *(u16x8*)(out + (size_t)gr * R + gcs * 8) = v;
  }
}

// ---------------- GEMM: BMx256 tile, BK=64, 8 waves, 3-buf A, direct-L2 B ---
// A (M x K) pre-swizzled, staged via global_load_lds (3-deep, counted vmcnt).
// Bt (N x K) pre-swizzled, fragments read DIRECTLY from global (L2-resident).
// Wave (wm = wid>>2, wn = wid&3): output WM x 64. One s_barrier per K-tile,
// vmcnt never drained to 0 in the main loop.
template<int BM, int WM, bool F32OUT>
__global__ __launch_bounds__(512, 2)
void gemm256(const u16* __restrict__ A, const u16* __restrict__ Bt,
             void* __restrict__ Cv, int M, int N, int K){
  constexpr int MF = WM / 16;            // m-frags per wave (8 or 4)
  constexpr int ALOADS = BM / 64;        // gload_lds per thread per K-tile
  __shared__ __align__(16) u16 Ab[3][BM * 64];
  const int tid = threadIdx.x;
  const int wid = tid >> 6, lane = tid & 63;
  const int g = lane >> 4, col = lane & 15;
  const int wm = wid >> 2, wn = wid & 3;
  const int swz = col & 7;

  // XCD-aware swizzle (grid = 256 blocks)
  int nb  = gridDim.x * gridDim.y;
  int lid = blockIdx.y * gridDim.x + blockIdx.x;
  int cpx = nb >> 3;
  int sid = (lid & 7) * cpx + (lid >> 3);
  int bx  = sid % gridDim.x, by = sid / gridDim.x;
  const int m0 = by * BM, n0 = bx * 256;

  f32x4 acc[MF][4];
#pragma unroll
  for (int i = 0; i < MF; i++)
#pragma unroll
    for (int j = 0; j < 4; j++) acc[i][j] = (f32x4){0.f, 0.f, 0.f, 0.f};

  const int arow = wid * 8 + (lane >> 3);
  const int acl  = (lane & 7) * 8;

  auto STAGE_A = [&](int bi, int k0){
#pragma unroll
    for (int j = 0; j < ALOADS; j++)
      gload_lds16(A + (size_t)(m0 + j * 64 + arow) * K + k0 + acl,
                  &Ab[bi][j * 4096 + wid * 512]);
  };

  const int NT = K >> 6;
  STAGE_A(0, 0);
  STAGE_A(1, 64);
  if (ALOADS == 4) asm volatile("s_waitcnt vmcnt(4)");
  else             asm volatile("s_waitcnt vmcnt(2)");
  __builtin_amdgcn_sched_barrier(0);
  __builtin_amdgcn_s_barrier();
  __builtin_amdgcn_sched_barrier(0);

  int cb = 0, sa = 2;
  for (int t = 0; t < NT; ++t){
    // B fragments straight from global (issued BEFORE the A-stage so the
    // compiler's B-use vmcnt wait retires A(t+1), not A(t+2)).
    bf16x8 bfr[4][2];
#pragma unroll
    for (int ni = 0; ni < 4; ni++){
      const u16* bp = Bt + (size_t)(n0 + wn * 64 + ni * 16 + col) * K + t * 64;
#pragma unroll
      for (int ks = 0; ks < 2; ks++)
        bfr[ni][ks] = *(const bf16x8*)(bp + (((ks * 4 + g) ^ swz) << 3));
    }
    __builtin_amdgcn_sched_barrier(0);
    if (t + 2 < NT) STAGE_A(sa, (t + 2) * 64);
    __builtin_amdgcn_sched_barrier(0);

    const u16* Ac = &Ab[cb][0];
#pragma unroll
    for (int ph = 0; ph < MF / 4; ++ph){
      bf16x8 afr[4][2];
#pragma unroll
      for (int m2 = 0; m2 < 4; m2++){
        int row = wm * WM + (ph * 4 + m2) * 16 + col;
#pragma unroll
        for (int ks = 0; ks < 2; ks++)
          afr[m2][ks] = *(const bf16x8*)&Ac[row * 64 + (((ks * 4 + g) ^ swz) << 3)];
      }
      __builtin_amdgcn_s_setprio(1);
#pragma unroll
      for (int m2 = 0; m2 < 4; m2++)
#pragma unroll
        for (int ni = 0; ni < 4; ni++)
#pragma unroll
          for (int ks = 0; ks < 2; ks++)
            acc[ph * 4 + m2][ni] =
                mfma16(afr[m2][ks], bfr[ni][ks], acc[ph * 4 + m2][ni]);
      __builtin_amdgcn_s_setprio(0);
    }

    // all my LDS reads retired -> next iter's stage may overwrite my buffer
    asm volatile("s_waitcnt lgkmcnt(0)");
    __builtin_amdgcn_sched_barrier(0);
    if (t + 2 < NT){
      if (ALOADS == 4) asm volatile("s_waitcnt vmcnt(4)");
      else             asm volatile("s_waitcnt vmcnt(2)");
    } else {
      asm volatile("s_waitcnt vmcnt(0)");
    }
    __builtin_amdgcn_sched_barrier(0);
    __builtin_amdgcn_s_barrier();
    __builtin_amdgcn_sched_barrier(0);
    cb = (cb == 2) ? 0 : cb + 1;
    sa = (sa == 2) ? 0 : sa + 1;
  }

#pragma unroll
  for (int mi = 0; mi < MF; mi++)
#pragma unroll
    for (int ni = 0; ni < 4; ni++)
#pragma unroll
      for (int r = 0; r < 4; r++){
        int row = m0 + wm * WM + mi * 16 + g * 4 + r;
        int cc  = n0 + wn * 64 + ni * 16 + col;
        if (F32OUT) ((float*)Cv)[(size_t)row * N + cc] = acc[mi][ni][r];
        else        ((u16*)Cv)[(size_t)row * N + cc] = f2bf(acc[mi][ni][r]);
      }
}

// ---------------- prep Q: RMSNorm+RoPE, QKV(b,s,2048) -> Qn (b,h,s,d) -------
__global__ void prep_q(const u16* __restrict__ qkv, u16* __restrict__ Qn,
                       const float* __restrict__ cosb, const float* __restrict__ sinb,
                       const float* __restrict__ w){
  int gid = blockIdx.x * 4 + (threadIdx.x >> 6);   // (b*16+h)*2048 + s
  int lane = threadIdx.x & 63;
  int s = gid & 2047;
  int bh = gid >> 11;
  int h = bh & 15, b = bh >> 4;
  float x = bf2f(qkv[((size_t)(b * 2048 + s)) * 2048 + h * 64 + lane]);
  float ss = x * x;
#pragma unroll
  for (int off = 32; off >= 1; off >>= 1) ss += __shfl_xor(ss, off, 64);
  float y = x * rsqrtf(ss * (1.f / 64.f) + 1e-6f);
  y *= w[lane];
  float yp = __shfl_xor(y, 16, 64);
  float rot = (lane & 16) ? yp : -yp;
  Qn[(size_t)gid * 64 + lane] = f2bf(y * cosb[s * 64 + lane] + rot * sinb[s * 64 + lane]);
}

// ---------------- prep K: RMSNorm+RoPE -> Kn (b,kvh,s,d) PRE-SWIZZLED -------
__global__ void prep_k(const u16* __restrict__ qkv, u16* __restrict__ Kn,
                       const float* __restrict__ cosb, const float* __restrict__ sinb,
                       const float* __restrict__ w){
  int gid = blockIdx.x * 4 + (threadIdx.x >> 6);   // (b*8+kvh)*2048 + s
  int lane = threadIdx.x & 63;
  int s = gid & 2047;
  int bk = gid >> 11;
  int kvh = bk & 7, b = bk >> 3;
  float x = bf2f(qkv[((size_t)(b * 2048 + s)) * 2048 + 1024 + kvh * 64 + lane]);
  float ss = x * x;
#pragma unroll
  for (int off = 32; off >= 1; off >>= 1) ss += __shfl_xor(ss, off, 64);
  float y = x * rsqrtf(ss * (1.f / 64.f) + 1e-6f);
  y *= w[lane];
  float yp = __shfl_xor(y, 16, 64);
  float rot = (lane & 16) ? yp : -yp;
  int swz = ((((lane >> 3) ^ s) & 7) << 3) | (lane & 7);
  Kn[(size_t)gid * 64 + swz] = f2bf(y * cosb[s * 64 + lane] + rot * sinb[s * 64 + lane]);
}

// ---------------- prep V: RMSNorm + transpose -> Vn (b,kvh,d,s) swizzled ----
__global__ __launch_bounds__(256)
void prep_v(const u16* __restrict__ qkv, u16* __restrict__ Vn){
  int blk = blockIdx.x;                 // b*256 + kvh*32 + stile
  int stile = blk & 31, kvh = (blk >> 5) & 7, b = blk >> 8;
  int wid = threadIdx.x >> 6, lane = threadIdx.x & 63;
  __shared__ u16 T[64][68];
#pragma unroll 4
  for (int j = 0; j < 16; j++){
    int sl = wid * 16 + j;
    int s = stile * 64 + sl;
    float x = bf2f(qkv[((size_t)(b * 2048 + s)) * 2048 + 1536 + kvh * 64 + lane]);
    float ss = x * x;
#pragma unroll
    for (int off = 32; off >= 1; off >>= 1) ss += __shfl_xor(ss, off, 64);
    T[sl][lane] = f2bf(x * rsqrtf(ss * (1.f / 64.f) + 1e-6f));
  }
  __syncthreads();
  size_t obase = ((size_t)(b * 8 + kvh) * 64) * 2048 + stile * 64;
#pragma unroll
  for (int it = 0; it < 2; it++){
    int t = it * 256 + threadIdx.x;
    int d = t >> 3, c = t & 7;
    int cl = c ^ (d & 7);
    u16x8 v;
#pragma unroll
    for (int i = 0; i < 8; i++) v[i] = T[cl * 8 + i][d];
    *(u16x8*)(Vn + obase + (size_t)d * 2048 + c * 8) = v;
  }
}

// ---------------- Flash attention (no-max softmax, 256q/block, 4 cg) --------
__global__ __launch_bounds__(256, 2)
void flash_attn(const u16* __restrict__ Qn, const u16* __restrict__ Kn,
                const u16* __restrict__ Vn, u16* __restrict__ AO){
  const int S = 2048;
  const float L2E = 1.4426950408889634f;
  const float C2 = 30.f;
  const int b = blockIdx.z, h = blockIdx.y, qt = blockIdx.x;
  const int kvh = h >> 1;
  const int wid = threadIdx.x >> 6, lane = threadIdx.x & 63;
  const int g = lane >> 4, col = lane & 15;
  const int q0 = qt * 256 + wid * 64;

  __shared__ __align__(16) u16 Klds[2][64 * 64];
  __shared__ __align__(16) u16 Vlds[2][64 * 64];
  __shared__ __align__(16) u16 Plds[4][16 * 64];

  bf16x8 ones;
#pragma unroll
  for (int i = 0; i < 8; i++) ones[i] = (__bf16)1.0f;

  bf16x8 aq[4][2];
#pragma unroll
  for (int cg = 0; cg < 4; cg++){
    const u16* qp = Qn + ((size_t)((b * 16 + h) * S) + q0 + cg * 16 + col) * 64;
    aq[cg][0] = *(const bf16x8*)(qp + g * 8);
    aq[cg][1] = *(const bf16x8*)(qp + 32 + g * 8);
  }

  const u16* Kbase = Kn + (size_t)(b * 8 + kvh) * S * 64;
  const u16* Vbase = Vn + (size_t)(b * 8 + kvh) * 64 * S;

  f32x4 acc[4][4];
  f32x4 lacc[4];
#pragma unroll
  for (int cg = 0; cg < 4; cg++){
    lacc[cg] = (f32x4){0.f, 0.f, 0.f, 0.f};
#pragma unroll
    for (int i = 0; i < 4; i++) acc[cg][i] = (f32x4){0.f, 0.f, 0.f, 0.f};
  }

  const int sw = col & 7;
  const int pswz = sw << 4;
  char* Pw = (char*)&Plds[wid][0];

  auto STAGE = [&](int bi, int kt){
    int kc0 = kt * 64;
#pragma unroll
    for (int cc = 0; cc < 2; cc++){
      int chunk = cc * 4 + wid;
      gload_lds16(Kbase + (size_t)kc0 * 64 + chunk * 512 + lane * 8,
                  &Klds[bi][chunk * 512]);
      int drow = chunk * 8 + (lane >> 3);
      gload_lds16(Vbase + (size_t)drow * S + kc0 + (lane & 7) * 8,
                  &Vlds[bi][chunk * 512]);
    }
  };

  int buf = 0;
  STAGE(0, 0);
  __syncthreads();

  for (int kt = 0; kt < S / 64; ++kt){
    if (kt + 1 < S / 64) STAGE(buf ^ 1, kt + 1);

    const u16* Kb = &Klds[buf][0];
    const u16* Vb = &Vlds[buf][0];

    bf16x8 kf[4][2], vf[4][2];
#pragma unroll
    for (int c = 0; c < 4; c++){
      const u16* kb = Kb + (c * 16 + col) * 64;
      kf[c][0] = *(const bf16x8*)(kb + (g ^ sw) * 8);
      kf[c][1] = *(const bf16x8*)(kb + ((4 + g) ^ sw) * 8);
      const u16* vb = Vb + (c * 16 + col) * 64;
      vf[c][0] = *(const bf16x8*)(vb + (g ^ sw) * 8);
      vf[c][1] = *(const bf16x8*)(vb + ((4 + g) ^ sw) * 8);
    }

#pragma unroll
    for (int cg = 0; cg < 4; cg++){
      f32x4 sf[4];
      __builtin_amdgcn_s_setprio(1);
#pragma unroll
      for (int c = 0; c < 4; c++){
        f32x4 z = (f32x4){0.f, 0.f, 0.f, 0.f};
        z = mfma16(kf[c][0], aq[cg][0], z);
        sf[c] = mfma16(kf[c][1], aq[cg][1], z);
      }
      __builtin_amdgcn_s_setprio(0);

#pragma unroll
      for (int c = 0; c < 4; c++){
        float p0 = exp2_fast(__builtin_fmaf(sf[c][0], L2E, -C2));
        float p1 = exp2_fast(__builtin_fmaf(sf[c][1], L2E, -C2));
        float p2 = exp2_fast(__builtin_fmaf(sf[c][2], L2E, -C2));
        float p3 = exp2_fast(__builtin_fmaf(sf[c][3], L2E, -C2));
        uint2 pw;
        pw.x = cvt_pk_bf16(p0, p1);
        pw.y = cvt_pk_bf16(p2, p3);
        *(uint2*)(Pw + ((col * 128 + c * 32 + g * 8) ^ pswz)) = pw;
      }

      bf16x8 pf0 = *(const bf16x8*)(Pw + ((col * 128 + g * 16) ^ pswz));
      bf16x8 pf1 = *(const bf16x8*)(Pw + ((col * 128 + 64 + g * 16) ^ pswz));
      __builtin_amdgcn_s_setprio(1);
#pragma unroll
      for (int cd = 0; cd < 4; cd++){
        acc[cg][cd] = mfma16(vf[cd][0], pf0, acc[cg][cd]);
        acc[cg][cd] = mfma16(vf[cd][1], pf1, acc[cg][cd]);
      }
      lacc[cg] = mfma16(ones, pf0, lacc[cg]);
      lacc[cg] = mfma16(ones, pf1, lacc[cg]);
      __builtin_amdgcn_s_setprio(0);
    }

    __syncthreads();
    buf ^= 1;
  }

#pragma unroll
  for (int cg = 0; cg < 4; cg++){
    float linv = 1.f / lacc[cg][0];
    int s = q0 + cg * 16 + col;
#pragma unroll
    for (int cd = 0; cd < 4; cd++){
      uint2 o;
      o.x = cvt_pk_bf16(acc[cg][cd][0] * linv, acc[cg][cd][1] * linv);
      o.y = cvt_pk_bf16(acc[cg][cd][2] * linv, acc[cg][cd][3] * linv);
      int pc = (cd * 2 + (g >> 1)) ^ sw;     // pre-swizzle for Wo GEMM
      *(uint2*)(AO + (size_t)(b * S + s) * 1024 + h * 64 + pc * 8 + (g & 1) * 4) = o;
    }
  }
}

// ---------------- host-side launch ------------------------------------------
extern "C" void kernel_launch(void* const* d_in, const int* in_sizes, int n_in,
                              void* d_out, int out_size, void* d_ws, size_t ws_size,
                              hipStream_t stream){
  const int Btok = 8192;          // B*S
  const float* hs   = (const float*)d_in[0];
  const float* cosb = (const float*)d_in[1];
  const float* sinb = (const float*)d_in[2];
  const float* Wq = (const float*)d_in[5];
  const float* Wk = (const float*)d_in[6];
  const float* Wv = (const float*)d_in[7];
  const float* Wo = (const float*)d_in[8];
  const float* qw = (const float*)d_in[9];
  const float* kw = (const float*)d_in[10];
  float* out = (float*)d_out;

  char* ws = (char*)d_ws;
  u16* hsB   = (u16*)ws;               ws += (size_t)Btok * 1024 * 2;   // 16MB
  u16* WqkvT = (u16*)ws;               ws += (size_t)2048 * 1024 * 2;   // 4MB
  u16* WoT   = (u16*)ws;               ws += (size_t)1024 * 1024 * 2;   // 2MB
  u16* QKV   = (u16*)ws;               ws += (size_t)Btok * 2048 * 2;   // 32MB
  u16* Qn    = (u16*)ws;               ws += (size_t)Btok * 1024 * 2;   // 16MB
  u16* Kn    = (u16*)ws;               ws += (size_t)Btok * 512  * 2;   // 8MB
  u16* Vn    = (u16*)ws;               ws += (size_t)Btok * 512  * 2;   // 8MB
  u16* AO    = hsB;                    // alias: hsB dead after QKV GEMM

  f32_to_bf16_swz<<<2048, 256, 0, stream>>>(hs, hsB, Btok * 128);

  dim3 tb(32, 32);
  conv_transpose_swz<<<dim3(32, 32), tb, 0, stream>>>(Wq, WqkvT,               1024, 1024);
  conv_transpose_swz<<<dim3(16, 32), tb, 0, stream>>>(Wk, WqkvT + 1024 * 1024, 1024, 512);
  conv_transpose_swz<<<dim3(16, 32), tb, 0, stream>>>(Wv, WqkvT + 1536 * 1024, 1024, 512);
  conv_transpose_swz<<<dim3(32, 32), tb, 0, stream>>>(Wo, WoT,                 1024, 1024);

  gemm256<256, 128, false><<<dim3(8, 32), 512, 0, stream>>>(hsB, WqkvT, QKV, Btok, 2048, 1024);

  prep_q<<<32768, 256, 0, stream>>>(QKV, Qn, cosb, sinb, qw);
  prep_k<<<16384, 256, 0, stream>>>(QKV, Kn, cosb, sinb, kw);
  prep_v<<<1024, 256, 0, stream>>>(QKV, Vn);

  flash_attn<<<dim3(8, 16, 4), 256, 0, stream>>>(Qn, Kn, Vn, AO);

  gemm256<128, 64, true><<<dim3(4, 64), 512, 0, stream>>>(AO, WoT, out, Btok, 1024, 1024);
}

// Round 9
// 185.573 us; speedup vs baseline: 1.1477x; 1.1058x over previous
//
#include <hip/hip_runtime.h>
#include <stdint.h>
#include <stddef.h>

typedef unsigned short u16;
typedef unsigned int   u32;
typedef unsigned short u16x8 __attribute__((ext_vector_type(8)));
typedef __attribute__((ext_vector_type(8))) __bf16 bf16x8;
typedef __attribute__((ext_vector_type(4))) float f32x4;

__device__ __forceinline__ float bf2f(u16 v){
  union { unsigned u; float f; } x; x.u = ((unsigned)v) << 16; return x.f;
}
__device__ __forceinline__ u16 f2bf(float f){
  union { float f; unsigned u; } x; x.f = f;
  return (u16)((x.u + 0x7fffu + ((x.u >> 16) & 1u)) >> 16);
}

__device__ __forceinline__ float exp2_fast(float x){
  float r; asm("v_exp_f32 %0, %1" : "=v"(r) : "v"(x)); return r;
}
__device__ __forceinline__ u32 cvt_pk_bf16(float lo, float hi){
  u32 r; asm("v_cvt_pk_bf16_f32 %0, %1, %2" : "=v"(r) : "v"(lo), "v"(hi)); return r;
}

__device__ __forceinline__ f32x4 mfma16(bf16x8 a, bf16x8 b, f32x4 c){
  return __builtin_amdgcn_mfma_f32_16x16x32_bf16(a, b, c, 0, 0, 0);
}

#define AS1 __attribute__((address_space(1)))
#define AS3 __attribute__((address_space(3)))
__device__ __forceinline__ void gload_lds16(const void* g, void* l){
  __builtin_amdgcn_global_load_lds((const AS1 void*)g, (AS3 void*)l, 16, 0, 0);
}

// ---------------- fp32 -> bf16, PRE-SWIZZLED chunks for BK=64 GEMM tiles ----
__global__ void f32_to_bf16_swz(const float* __restrict__ in, u16* __restrict__ out,
                                int total_chunks){
  for (int i = blockIdx.x * blockDim.x + threadIdx.x; i < total_chunks;
       i += gridDim.x * blockDim.x){
    int row = i >> 7, c = i & 127;
    int cs = (c & ~7) | ((c & 7) ^ (row & 7));
    const float* p = in + ((size_t)i << 3);
    float4 v0 = *(const float4*)p;
    float4 v1 = *(const float4*)(p + 4);
    u16x8 o = { f2bf(v0.x), f2bf(v0.y), f2bf(v0.z), f2bf(v0.w),
                f2bf(v1.x), f2bf(v1.y), f2bf(v1.z), f2bf(v1.w) };
    *(u16x8*)(out + (((size_t)row << 7) + cs) * 8) = o;
  }
}

// ---------------- transpose+convert fp32 (R x C) -> bf16 (C x R), swizzled --
__global__ void conv_transpose_swz(const float* __restrict__ in, u16* __restrict__ out,
                                   int R, int C){
  __shared__ float t[32][33];
  int c0 = blockIdx.x * 32, r0 = blockIdx.y * 32;
  int tx = threadIdx.x, ty = threadIdx.y;
  t[ty][tx] = in[(size_t)(r0 + ty) * C + c0 + tx];
  __syncthreads();
  int tid = ty * 32 + tx;
  if (tid < 128){
    int orow = tid >> 2, oc = tid & 3;
    int gr = c0 + orow;
    int gc = (r0 >> 3) + oc;
    int gcs = (gc & ~7) | ((gc & 7) ^ (gr & 7));
    u16x8 v;
#pragma unroll
    for (int i = 0; i < 8; i++) v[i] = f2bf(t[oc * 8 + i][orow]);
    *(u16x8*)(out + (size_t)gr * R + gcs * 8) = v;
  }
}

// ---------------- pack cos/sin into float2 table ----------------------------
__global__ void pack_cs(const float* __restrict__ cosb, const float* __restrict__ sinb,
                        float2* __restrict__ cs, int n){
  int i = blockIdx.x * 256 + threadIdx.x;
  if (i < n) cs[i] = (float2){cosb[i], sinb[i]};
}

// ---------------- GEMM: BMx256 tile, BK=64, 8 waves, 3-buf A, direct-L2 B ---
// EPI: 0 = bf16 C, 1 = fused QKV epilogue (RMSNorm+RoPE+relayout), 2 = f32 C.
template<int BM, int WM, int EPI>
__global__ __launch_bounds__(512, 2)
void gemm256(const u16* __restrict__ A, const u16* __restrict__ Bt,
             void* __restrict__ Cv, int M, int N, int K,
             const float2* __restrict__ cs, const float* __restrict__ qw,
             const float* __restrict__ kw, u16* __restrict__ Qn,
             u16* __restrict__ Kn, u16* __restrict__ Vn){
  constexpr int MF = WM / 16;
  constexpr int ALOADS = BM / 64;
  __shared__ __align__(16) u16 Ab[3][BM * 64];
  const int tid = threadIdx.x;
  const int wid = tid >> 6, lane = tid & 63;
  const int g = lane >> 4, col = lane & 15;
  const int wm = wid >> 2, wn = wid & 3;
  const int swz = col & 7;

  int nb  = gridDim.x * gridDim.y;
  int lid = blockIdx.y * gridDim.x + blockIdx.x;
  int cpx = nb >> 3;
  int sid = (lid & 7) * cpx + (lid >> 3);
  int bx  = sid % gridDim.x, by = sid / gridDim.x;
  const int m0 = by * BM, n0 = bx * 256;

  f32x4 acc[MF][4];
#pragma unroll
  for (int i = 0; i < MF; i++)
#pragma unroll
    for (int j = 0; j < 4; j++) acc[i][j] = (f32x4){0.f, 0.f, 0.f, 0.f};

  const int arow = wid * 8 + (lane >> 3);
  const int acl  = (lane & 7) * 8;

  auto STAGE_A = [&](int bi, int k0){
#pragma unroll
    for (int j = 0; j < ALOADS; j++)
      gload_lds16(A + (size_t)(m0 + j * 64 + arow) * K + k0 + acl,
                  &Ab[bi][j * 4096 + wid * 512]);
  };

  const int NT = K >> 6;
  STAGE_A(0, 0);
  STAGE_A(1, 64);
  if (ALOADS == 4) asm volatile("s_waitcnt vmcnt(4)");
  else             asm volatile("s_waitcnt vmcnt(2)");
  __builtin_amdgcn_sched_barrier(0);
  __builtin_amdgcn_s_barrier();
  __builtin_amdgcn_sched_barrier(0);

  int cb = 0, sa = 2;
  for (int t = 0; t < NT; ++t){
    bf16x8 bfr[4][2];
#pragma unroll
    for (int ni = 0; ni < 4; ni++){
      const u16* bp = Bt + (size_t)(n0 + wn * 64 + ni * 16 + col) * K + t * 64;
#pragma unroll
      for (int ks = 0; ks < 2; ks++)
        bfr[ni][ks] = *(const bf16x8*)(bp + (((ks * 4 + g) ^ swz) << 3));
    }
    __builtin_amdgcn_sched_barrier(0);
    if (t + 2 < NT) STAGE_A(sa, (t + 2) * 64);
    __builtin_amdgcn_sched_barrier(0);

    const u16* Ac = &Ab[cb][0];
#pragma unroll
    for (int ph = 0; ph < MF / 4; ++ph){
      bf16x8 afr[4][2];
#pragma unroll
      for (int m2 = 0; m2 < 4; m2++){
        int row = wm * WM + (ph * 4 + m2) * 16 + col;
#pragma unroll
        for (int ks = 0; ks < 2; ks++)
          afr[m2][ks] = *(const bf16x8*)&Ac[row * 64 + (((ks * 4 + g) ^ swz) << 3)];
      }
      __builtin_amdgcn_s_setprio(1);
#pragma unroll
      for (int m2 = 0; m2 < 4; m2++)
#pragma unroll
        for (int ni = 0; ni < 4; ni++)
#pragma unroll
          for (int ks = 0; ks < 2; ks++)
            acc[ph * 4 + m2][ni] =
                mfma16(afr[m2][ks], bfr[ni][ks], acc[ph * 4 + m2][ni]);
      __builtin_amdgcn_s_setprio(0);
    }

    asm volatile("s_waitcnt lgkmcnt(0)");
    __builtin_amdgcn_sched_barrier(0);
    if (t + 2 < NT){
      if (ALOADS == 4) asm volatile("s_waitcnt vmcnt(4)");
      else             asm volatile("s_waitcnt vmcnt(2)");
    } else {
      asm volatile("s_waitcnt vmcnt(0)");
    }
    __builtin_amdgcn_sched_barrier(0);
    __builtin_amdgcn_s_barrier();
    __builtin_amdgcn_sched_barrier(0);
    cb = (cb == 2) ? 0 : cb + 1;
    sa = (sa == 2) ? 0 : sa + 1;
  }

  if (EPI == 1){
    // ---- fused RMSNorm + RoPE + relayout epilogue ----
    const int colbase = n0 + wn * 64;    // wave owns one 64-wide head
    const int t0 = m0 + wm * WM;         // token base (same batch for all rows)
    const int bb = t0 >> 11;
    if (colbase < 1536){
      const bool isQ = colbase < 1024;
      const int head = isQ ? (colbase >> 6) : ((colbase - 1024) >> 6);
      const float* wp = isQ ? qw : kw;
      float wv[4];
#pragma unroll
      for (int ni = 0; ni < 4; ni++) wv[ni] = wp[ni * 16 + col];
      u16* outp = isQ ? Qn : Kn;
      size_t hb = isQ ? ((size_t)(bb * 16 + head) * 2048)
                      : ((size_t)(bb * 8 + head) * 2048);
#pragma unroll
      for (int mi = 0; mi < MF; mi++){
        f32x4 ssv = (f32x4){0.f, 0.f, 0.f, 0.f};
#pragma unroll
        for (int ni = 0; ni < 4; ni++)
#pragma unroll
          for (int r = 0; r < 4; r++) ssv[r] += acc[mi][ni][r] * acc[mi][ni][r];
#pragma unroll
        for (int off = 1; off < 16; off <<= 1)
#pragma unroll
          for (int r = 0; r < 4; r++) ssv[r] += __shfl_xor(ssv[r], off, 64);
        f32x4 rinv;
#pragma unroll
        for (int r = 0; r < 4; r++) rinv[r] = rsqrtf(ssv[r] * (1.f / 64.f) + 1e-6f);
        int s0 = (t0 + mi * 16 + g * 4) & 2047;
#pragma unroll
        for (int np = 0; np < 2; np++){
          int d0 = np * 32 + col, d1 = d0 + 16;
#pragma unroll
          for (int r = 0; r < 4; r++){
            int s = s0 + r;
            float y0 = acc[mi][np * 2][r]     * rinv[r] * wv[np * 2];
            float y1 = acc[mi][np * 2 + 1][r] * rinv[r] * wv[np * 2 + 1];
            float2 c0 = cs[s * 64 + d0];
            float2 c1 = cs[s * 64 + d1];
            float o0 = y0 * c0.x - y1 * c0.y;   // d&16==0: rot = -y[d+16]
            float o1 = y1 * c1.x + y0 * c1.y;   // d&16==1: rot = +y[d-16]
            if (isQ){
              outp[(hb + s) * 64 + d0] = f2bf(o0);
              outp[(hb + s) * 64 + d1] = f2bf(o1);
            } else {
              int z0 = ((((d0 >> 3) ^ s) & 7) << 3) | (d0 & 7);
              int z1 = ((((d1 >> 3) ^ s) & 7) << 3) | (d1 & 7);
              outp[(hb + s) * 64 + z0] = f2bf(o0);
              outp[(hb + s) * 64 + z1] = f2bf(o1);
            }
          }
        }
      }
    } else {
      const int kvh = (colbase - 1536) >> 6;
      const size_t vb0 = (size_t)(bb * 8 + kvh) * 64;
#pragma unroll
      for (int mi = 0; mi < MF; mi++){
        f32x4 ssv = (f32x4){0.f, 0.f, 0.f, 0.f};
#pragma unroll
        for (int ni = 0; ni < 4; ni++)
#pragma unroll
          for (int r = 0; r < 4; r++) ssv[r] += acc[mi][ni][r] * acc[mi][ni][r];
#pragma unroll
        for (int off = 1; off < 16; off <<= 1)
#pragma unroll
          for (int r = 0; r < 4; r++) ssv[r] += __shfl_xor(ssv[r], off, 64);
        f32x4 rinv;
#pragma unroll
        for (int r = 0; r < 4; r++) rinv[r] = rsqrtf(ssv[r] * (1.f / 64.f) + 1e-6f);
        int s0 = (t0 + mi * 16 + g * 4) & 2047;
#pragma unroll
        for (int ni = 0; ni < 4; ni++){
          int d = ni * 16 + col;
          uint2 o;
          o.x = cvt_pk_bf16(acc[mi][ni][0] * rinv[0], acc[mi][ni][1] * rinv[1]);
          o.y = cvt_pk_bf16(acc[mi][ni][2] * rinv[2], acc[mi][ni][3] * rinv[3]);
          size_t addr = (vb0 + d) * 2048 + (s0 & ~63)
                      + ((((s0 >> 3) ^ (d & 7)) & 7) << 3) + (s0 & 7);
          *(uint2*)(Vn + addr) = o;
        }
      }
    }
    return;
  }

#pragma unroll
  for (int mi = 0; mi < MF; mi++)
#pragma unroll
    for (int ni = 0; ni < 4; ni++)
#pragma unroll
      for (int r = 0; r < 4; r++){
        int row = m0 + wm * WM + mi * 16 + g * 4 + r;
        int cc  = n0 + wn * 64 + ni * 16 + col;
        if (EPI == 2) ((float*)Cv)[(size_t)row * N + cc] = acc[mi][ni][r];
        else          ((u16*)Cv)[(size_t)row * N + cc] = f2bf(acc[mi][ni][r]);
      }
}

// ---------------- Flash attention (no-max softmax, 256q/block, 4 cg) --------
__global__ __launch_bounds__(256, 2)
void flash_attn(const u16* __restrict__ Qn, const u16* __restrict__ Kn,
                const u16* __restrict__ Vn, u16* __restrict__ AO){
  const int S = 2048;
  const float L2E = 1.4426950408889634f;
  const float C2 = 30.f;
  const int b = blockIdx.z, h = blockIdx.y, qt = blockIdx.x;
  const int kvh = h >> 1;
  const int wid = threadIdx.x >> 6, lane = threadIdx.x & 63;
  const int g = lane >> 4, col = lane & 15;
  const int q0 = qt * 256 + wid * 64;

  __shared__ __align__(16) u16 Klds[2][64 * 64];
  __shared__ __align__(16) u16 Vlds[2][64 * 64];
  __shared__ __align__(16) u16 Plds[4][16 * 64];

  bf16x8 ones;
#pragma unroll
  for (int i = 0; i < 8; i++) ones[i] = (__bf16)1.0f;

  bf16x8 aq[4][2];
#pragma unroll
  for (int cg = 0; cg < 4; cg++){
    const u16* qp = Qn + ((size_t)((b * 16 + h) * S) + q0 + cg * 16 + col) * 64;
    aq[cg][0] = *(const bf16x8*)(qp + g * 8);
    aq[cg][1] = *(const bf16x8*)(qp + 32 + g * 8);
  }

  const u16* Kbase = Kn + (size_t)(b * 8 + kvh) * S * 64;
  const u16* Vbase = Vn + (size_t)(b * 8 + kvh) * 64 * S;

  f32x4 acc[4][4];
  f32x4 lacc[4];
#pragma unroll
  for (int cg = 0; cg < 4; cg++){
    lacc[cg] = (f32x4){0.f, 0.f, 0.f, 0.f};
#pragma unroll
    for (int i = 0; i < 4; i++) acc[cg][i] = (f32x4){0.f, 0.f, 0.f, 0.f};
  }

  const int sw = col & 7;
  const int pswz = sw << 4;
  char* Pw = (char*)&Plds[wid][0];

  auto STAGE = [&](int bi, int kt){
    int kc0 = kt * 64;
#pragma unroll
    for (int cc = 0; cc < 2; cc++){
      int chunk = cc * 4 + wid;
      gload_lds16(Kbase + (size_t)kc0 * 64 + chunk * 512 + lane * 8,
                  &Klds[bi][chunk * 512]);
      int drow = chunk * 8 + (lane >> 3);
      gload_lds16(Vbase + (size_t)drow * S + kc0 + (lane & 7) * 8,
                  &Vlds[bi][chunk * 512]);
    }
  };

  int buf = 0;
  STAGE(0, 0);
  __syncthreads();

  for (int kt = 0; kt < S / 64; ++kt){
    if (kt + 1 < S / 64) STAGE(buf ^ 1, kt + 1);

    const u16* Kb = &Klds[buf][0];
    const u16* Vb = &Vlds[buf][0];

    bf16x8 kf[4][2], vf[4][2];
#pragma unroll
    for (int c = 0; c < 4; c++){
      const u16* kb = Kb + (c * 16 + col) * 64;
      kf[c][0] = *(const bf16x8*)(kb + (g ^ sw) * 8);
      kf[c][1] = *(const bf16x8*)(kb + ((4 + g) ^ sw) * 8);
      const u16* vb = Vb + (c * 16 + col) * 64;
      vf[c][0] = *(const bf16x8*)(vb + (g ^ sw) * 8);
      vf[c][1] = *(const bf16x8*)(vb + ((4 + g) ^ sw) * 8);
    }

#pragma unroll
    for (int cg = 0; cg < 4; cg++){
      f32x4 sf[4];
      __builtin_amdgcn_s_setprio(1);
#pragma unroll
      for (int c = 0; c < 4; c++){
        f32x4 z = (f32x4){0.f, 0.f, 0.f, 0.f};
        z = mfma16(kf[c][0], aq[cg][0], z);
        sf[c] = mfma16(kf[c][1], aq[cg][1], z);
      }
      __builtin_amdgcn_s_setprio(0);

#pragma unroll
      for (int c = 0; c < 4; c++){
        float p0 = exp2_fast(__builtin_fmaf(sf[c][0], L2E, -C2));
        float p1 = exp2_fast(__builtin_fmaf(sf[c][1], L2E, -C2));
        float p2 = exp2_fast(__builtin_fmaf(sf[c][2], L2E, -C2));
        float p3 = exp2_fast(__builtin_fmaf(sf[c][3], L2E, -C2));
        uint2 pw;
        pw.x = cvt_pk_bf16(p0, p1);
        pw.y = cvt_pk_bf16(p2, p3);
        *(uint2*)(Pw + ((col * 128 + c * 32 + g * 8) ^ pswz)) = pw;
      }

      bf16x8 pf0 = *(const bf16x8*)(Pw + ((col * 128 + g * 16) ^ pswz));
      bf16x8 pf1 = *(const bf16x8*)(Pw + ((col * 128 + 64 + g * 16) ^ pswz));
      __builtin_amdgcn_s_setprio(1);
#pragma unroll
      for (int cd = 0; cd < 4; cd++){
        acc[cg][cd] = mfma16(vf[cd][0], pf0, acc[cg][cd]);
        acc[cg][cd] = mfma16(vf[cd][1], pf1, acc[cg][cd]);
      }
      lacc[cg] = mfma16(ones, pf0, lacc[cg]);
      lacc[cg] = mfma16(ones, pf1, lacc[cg]);
      __builtin_amdgcn_s_setprio(0);
    }

    __syncthreads();
    buf ^= 1;
  }

#pragma unroll
  for (int cg = 0; cg < 4; cg++){
    float linv = 1.f / lacc[cg][0];
    int s = q0 + cg * 16 + col;
#pragma unroll
    for (int cd = 0; cd < 4; cd++){
      uint2 o;
      o.x = cvt_pk_bf16(acc[cg][cd][0] * linv, acc[cg][cd][1] * linv);
      o.y = cvt_pk_bf16(acc[cg][cd][2] * linv, acc[cg][cd][3] * linv);
      int pc = (cd * 2 + (g >> 1)) ^ sw;     // pre-swizzle for Wo GEMM
      *(uint2*)(AO + (size_t)(b * S + s) * 1024 + h * 64 + pc * 8 + (g & 1) * 4) = o;
    }
  }
}

// ---------------- host-side launch ------------------------------------------
extern "C" void kernel_launch(void* const* d_in, const int* in_sizes, int n_in,
                              void* d_out, int out_size, void* d_ws, size_t ws_size,
                              hipStream_t stream){
  const int Btok = 8192;          // B*S
  const float* hs   = (const float*)d_in[0];
  const float* cosb = (const float*)d_in[1];
  const float* sinb = (const float*)d_in[2];
  const float* Wq = (const float*)d_in[5];
  const float* Wk = (const float*)d_in[6];
  const float* Wv = (const float*)d_in[7];
  const float* Wo = (const float*)d_in[8];
  const float* qw = (const float*)d_in[9];
  const float* kw = (const float*)d_in[10];
  float* out = (float*)d_out;

  char* ws = (char*)d_ws;
  u16* hsB   = (u16*)ws;               ws += (size_t)Btok * 1024 * 2;   // 16MB
  u16* WqkvT = (u16*)ws;               ws += (size_t)2048 * 1024 * 2;   // 4MB
  u16* WoT   = (u16*)ws;               ws += (size_t)1024 * 1024 * 2;   // 2MB
  u16* Qn    = (u16*)ws;               ws += (size_t)Btok * 1024 * 2;   // 16MB
  u16* Kn    = (u16*)ws;               ws += (size_t)Btok * 512  * 2;   // 8MB
  u16* Vn    = (u16*)ws;               ws += (size_t)Btok * 512  * 2;   // 8MB
  float2* cst = (float2*)ws;           ws += (size_t)2048 * 64 * 8;     // 1MB
  u16* AO    = hsB;                    // alias: hsB dead after QKV GEMM

  f32_to_bf16_swz<<<2048, 256, 0, stream>>>(hs, hsB, Btok * 128);

  dim3 tb(32, 32);
  conv_transpose_swz<<<dim3(32, 32), tb, 0, stream>>>(Wq, WqkvT,               1024, 1024);
  conv_transpose_swz<<<dim3(16, 32), tb, 0, stream>>>(Wk, WqkvT + 1024 * 1024, 1024, 512);
  conv_transpose_swz<<<dim3(16, 32), tb, 0, stream>>>(Wv, WqkvT + 1536 * 1024, 1024, 512);
  conv_transpose_swz<<<dim3(32, 32), tb, 0, stream>>>(Wo, WoT,                 1024, 1024);
  pack_cs<<<512, 256, 0, stream>>>(cosb, sinb, cst, 2048 * 64);

  gemm256<256, 128, 1><<<dim3(8, 32), 512, 0, stream>>>(
      hsB, WqkvT, nullptr, Btok, 2048, 1024, cst, qw, kw, Qn, Kn, Vn);

  flash_attn<<<dim3(8, 16, 4), 256, 0, stream>>>(Qn, Kn, Vn, AO);

  gemm256<128, 64, 2><<<dim3(4, 64), 512, 0, stream>>>(
      AO, WoT, out, Btok, 1024, 1024, nullptr, nullptr, nullptr,
      nullptr, nullptr, nullptr);
}